// Round 1
// baseline (1239.755 us; speedup 1.0000x reference)
//
#include <hip/hip_runtime.h>
#include <stdint.h>

#define TB 256

// ---------------------------------------------------------------------------
// Kernel A: per-query preprocessing.
//   - softmax over C=2 logits -> (p0, p1)
//   - absolute coords ax = px*img_h, ay = py*img_w
//   - mask gather byte offset off = clip((int)ay,0,w-1)*W + clip((int)ax,0,h-1)
//     (faithful to reference: xs from dim0 scaled by img_h used as COLUMN,
//      ys from dim1 used as ROW; H==W so dims are consistent)
// ---------------------------------------------------------------------------
__global__ void prep_kernel(const float* __restrict__ logits,
                            const float* __restrict__ points,
                            const int* __restrict__ img_h_p,
                            const int* __restrict__ img_w_p,
                            float4* __restrict__ qdata,
                            int* __restrict__ offs,
                            int Q) {
    int q = blockIdx.x * blockDim.x + threadIdx.x;
    if (q >= Q) return;
    int h = *img_h_p, w = *img_w_p;
    float l0 = logits[2 * q], l1 = logits[2 * q + 1];
    float m  = fmaxf(l0, l1);
    float e0 = __expf(l0 - m), e1 = __expf(l1 - m);
    float rs = 1.0f / (e0 + e1);
    float px = points[2 * q], py = points[2 * q + 1];
    float ax = px * (float)h;
    float ay = py * (float)w;
    int xs = (int)ax; xs = min(max(xs, 0), h - 1);
    int ys = (int)ay; ys = min(max(ys, 0), w - 1);
    qdata[q] = make_float4(e0 * rs, e1 * rs, ax, ay);
    offs[q]  = ys * w + xs;   // row stride = mask width = img_w
}

// ---------------------------------------------------------------------------
// Kernel B: one block per target t.
//   Phase 1: stream the 256KB bool slice coalesced, bit-pack into 32KB LDS.
//            (numpy bool bytes are exactly 0/1 -> LSB-gather multiply trick)
//   Phase 2: gather the Q per-query bits from LDS, ballot into 64-bit groups,
//            write packed[g][t]  (layout: group-major so kernel C reads
//            consecutive t coalesced).
// ---------------------------------------------------------------------------
__global__ void pack_gather_kernel(const unsigned char* __restrict__ masks,
                                   const int* __restrict__ offs,
                                   unsigned long long* __restrict__ packed,
                                   int Q, int T, int HW) {
    extern __shared__ uint32_t bits[];   // HW/32 words = HW/8 bytes
    const int t = blockIdx.x;
    const uint4* src = (const uint4*)(masks + (size_t)t * HW);
    const int words = HW >> 5;           // 32 bytes -> 1 word

    const uint32_t M = 0x01010101u;
    const uint32_t P = 0x10204080u;      // gathers 4 byte-LSBs into bits 28..31

    for (int wi = threadIdx.x; wi < words; wi += TB) {
        uint4 a = src[2 * wi];
        uint4 b = src[2 * wi + 1];
        uint32_t w;
        w  = ((a.x & M) * P) >> 28;
        w |= (((a.y & M) * P) >> 28) << 4;
        w |= (((a.z & M) * P) >> 28) << 8;
        w |= (((a.w & M) * P) >> 28) << 12;
        w |= (((b.x & M) * P) >> 28) << 16;
        w |= (((b.y & M) * P) >> 28) << 20;
        w |= (((b.z & M) * P) >> 28) << 24;
        w |= (((b.w & M) * P) >> 28) << 28;
        bits[wi] = w;
    }
    __syncthreads();

    const int lane   = threadIdx.x & 63;
    const int wave   = threadIdx.x >> 6;
    const int nwaves = TB >> 6;
    const int groups = Q >> 6;
    for (int g = wave; g < groups; g += nwaves) {
        int off = offs[(g << 6) + lane];
        uint32_t b = (bits[off >> 5] >> (off & 31)) & 1u;
        unsigned long long bal = __ballot(b);
        if (lane == 0) packed[(size_t)g * T + t] = bal;
    }
}

// ---------------------------------------------------------------------------
// Kernel C: one block per query q; thread j computes t = 4j..4j+3.
//   All global reads are coalesced (packed row, tgt arrays) or broadcast
//   (qdata[q]); output stored as float4.
// ---------------------------------------------------------------------------
__device__ __forceinline__ float costf(float p0, float p1, float ax, float ay,
                                       float tx, float ty, int id,
                                       unsigned int inside) {
    float dx = ax - tx, dy = ay - ty;
    float d2 = dx * dx + dy * dy;
    float cp = sqrtf(d2);                       // cost_point
    float cc = -(id ? p1 : p0);                 // cost_class
    float ga = __expf(d2 * (-1.0f / 200.0f));   // SIGMA=10 -> 1/(2*sigma^2)
    float cm = inside ? (1.0f - ga) : 10.0f;    // cost_mask
    return cp + cc + cm;
}

__global__ void cost_kernel(const float4* __restrict__ qdata,
                            const unsigned long long* __restrict__ packed,
                            const float* __restrict__ tpts,
                            const int* __restrict__ tids,
                            float* __restrict__ out,
                            int T) {
    const int q = blockIdx.x;
    const float4 qd = qdata[q];                 // broadcast
    const int g  = q >> 6;
    const int bp = q & 63;
    const unsigned long long* prow = packed + (size_t)g * T;

    const int j  = threadIdx.x;                 // T == 4*TB assumed (1024/256)
    float4 tp01 = ((const float4*)tpts)[2 * j]; // (x0,y0,x1,y1)
    float4 tp23 = ((const float4*)tpts)[2 * j + 1];
    int4   id4  = ((const int4*)tids)[j];
    ulonglong2 m01 = ((const ulonglong2*)prow)[2 * j];
    ulonglong2 m23 = ((const ulonglong2*)prow)[2 * j + 1];

    float4 o;
    o.x = costf(qd.x, qd.y, qd.z, qd.w, tp01.x, tp01.y, id4.x,
                (unsigned int)((m01.x >> bp) & 1ull));
    o.y = costf(qd.x, qd.y, qd.z, qd.w, tp01.z, tp01.w, id4.y,
                (unsigned int)((m01.y >> bp) & 1ull));
    o.z = costf(qd.x, qd.y, qd.z, qd.w, tp23.x, tp23.y, id4.z,
                (unsigned int)((m23.x >> bp) & 1ull));
    o.w = costf(qd.x, qd.y, qd.z, qd.w, tp23.z, tp23.w, id4.w,
                (unsigned int)((m23.y >> bp) & 1ull));

    ((float4*)(out + (size_t)q * T))[j] = o;
}

// ---------------------------------------------------------------------------
extern "C" void kernel_launch(void* const* d_in, const int* in_sizes, int n_in,
                              void* d_out, int out_size, void* d_ws, size_t ws_size,
                              hipStream_t stream) {
    const float* logits = (const float*)d_in[0];          // [bs,nq,2] f32
    const float* points = (const float*)d_in[1];          // [bs,nq,2] f32
    const float* tpts   = (const float*)d_in[2];          // [T,2] f32
    const int*   tids   = (const int*)d_in[3];            // [T] i32
    const unsigned char* masks = (const unsigned char*)d_in[4]; // [T,H,W] bool
    const int*   img_h  = (const int*)d_in[5];            // scalar
    const int*   img_w  = (const int*)d_in[6];            // scalar
    float* out = (float*)d_out;

    const int Q  = in_sizes[1] / 2;                       // 16384
    const int T  = in_sizes[3];                           // 1024
    const int HW = (int)(in_sizes[4] / (size_t)T);        // 262144

    // workspace layout: [ qdata float4 x Q | offs int x Q | packed u64 x (Q/64)*T ]
    char* ws = (char*)d_ws;
    float4* qdata = (float4*)ws;
    int*    offs  = (int*)(ws + (size_t)Q * 16);
    unsigned long long* packed =
        (unsigned long long*)(ws + (size_t)Q * 16 + (size_t)Q * 4);

    prep_kernel<<<(Q + TB - 1) / TB, TB, 0, stream>>>(
        logits, points, img_h, img_w, qdata, offs, Q);

    pack_gather_kernel<<<T, TB, HW / 8, stream>>>(
        masks, offs, packed, Q, T, HW);

    cost_kernel<<<Q, TB, 0, stream>>>(qdata, packed, tpts, tids, out, T);
}

// Round 2
// 1222.872 us; speedup vs baseline: 1.0138x; 1.0138x over previous
//
#include <hip/hip_runtime.h>
#include <stdint.h>

#define TB 256

typedef uint32_t u32x4 __attribute__((ext_vector_type(4)));
typedef float    f32x4 __attribute__((ext_vector_type(4)));

// ---------------------------------------------------------------------------
// Kernel A: per-query preprocessing (math bit-identical to round-1 version).
//   softmax over C=2 logits, absolute coords, clipped mask byte offset.
// ---------------------------------------------------------------------------
__global__ __launch_bounds__(TB) void prep_kernel(
        const float* __restrict__ logits,
        const float* __restrict__ points,
        const int* __restrict__ img_h_p,
        const int* __restrict__ img_w_p,
        float4* __restrict__ qdata,
        int* __restrict__ offs,
        int Q) {
    int q = blockIdx.x * blockDim.x + threadIdx.x;
    if (q >= Q) return;
    int h = *img_h_p, w = *img_w_p;
    float l0 = logits[2 * q], l1 = logits[2 * q + 1];
    float m  = fmaxf(l0, l1);
    float e0 = __expf(l0 - m), e1 = __expf(l1 - m);
    float rs = 1.0f / (e0 + e1);
    float px = points[2 * q], py = points[2 * q + 1];
    float ax = px * (float)h;
    float ay = py * (float)w;
    int xs = (int)ax; xs = min(max(xs, 0), h - 1);
    int ys = (int)ay; ys = min(max(ys, 0), w - 1);
    qdata[q] = make_float4(e0 * rs, e1 * rs, ax, ay);
    offs[q]  = ys * w + xs;   // row stride = mask width = img_w
}

// ---------------------------------------------------------------------------
// Kernel B: TWO blocks per target t (halves of the slice) for occupancy.
//   grid = 2*T, 16KB LDS/block -> 8 blocks/CU, 32 waves/CU.
//   Phase 1: stream 128KB half-slice (nontemporal, unroll 8 for bytes in
//            flight), bit-pack into LDS.
//   Phase 2: predicated gather of the Q bits that fall in this half; ballot
//            into 64-bit groups; write per-half row packed[(2g+h)][t].
// ---------------------------------------------------------------------------
__global__ __launch_bounds__(TB) void pack_gather_kernel(
        const unsigned char* __restrict__ masks,
        const int* __restrict__ offs,
        unsigned long long* __restrict__ packed,
        int Q, int T, int HW) {
    extern __shared__ uint32_t bits[];      // HW/64 words = HW/16 bytes
    const int t = blockIdx.x >> 1;
    const int h = blockIdx.x & 1;
    const int halfPix = HW >> 1;
    const u32x4* src =
        (const u32x4*)(masks + (size_t)t * HW + (size_t)h * halfPix);
    const int words = HW >> 6;              // packed u32 words per half

    const uint32_t M = 0x01010101u;
    const uint32_t P = 0x10204080u;         // gathers 4 byte-LSBs into bits 28..31

    #pragma unroll 8
    for (int wi = threadIdx.x; wi < words; wi += TB) {
        u32x4 a = __builtin_nontemporal_load(src + 2 * wi);
        u32x4 b = __builtin_nontemporal_load(src + 2 * wi + 1);
        uint32_t w;
        w  = ((a.x & M) * P) >> 28;
        w |= (((a.y & M) * P) >> 28) << 4;
        w |= (((a.z & M) * P) >> 28) << 8;
        w |= (((a.w & M) * P) >> 28) << 12;
        w |= (((b.x & M) * P) >> 28) << 16;
        w |= (((b.y & M) * P) >> 28) << 20;
        w |= (((b.z & M) * P) >> 28) << 24;
        w |= (((b.w & M) * P) >> 28) << 28;
        bits[wi] = w;
    }
    __syncthreads();

    const int lane   = threadIdx.x & 63;
    const int wave   = threadIdx.x >> 6;
    const int nwaves = TB >> 6;
    const int groups = Q >> 6;
    #pragma unroll 2
    for (int g = wave; g < groups; g += nwaves) {
        int off = offs[(g << 6) + lane];
        uint32_t li = (uint32_t)(off - h * halfPix);   // unsigned wrap if other half
        int ok = li < (uint32_t)halfPix;
        uint32_t word = bits[ok ? (li >> 5) : 0];
        uint32_t b = ok ? ((word >> (li & 31)) & 1u) : 0u;
        unsigned long long bal = __ballot(b);
        if (lane == 0) packed[((size_t)(g << 1) + h) * T + t] = bal;
    }
}

// ---------------------------------------------------------------------------
// Kernel C: one block per query q; thread j computes t = 4j..4j+3.
//   ORs the two half-ballot rows; nontemporal float4 output stores.
// ---------------------------------------------------------------------------
__device__ __forceinline__ float costf(float p0, float p1, float ax, float ay,
                                       float tx, float ty, int id,
                                       unsigned int inside) {
    float dx = ax - tx, dy = ay - ty;
    float d2 = dx * dx + dy * dy;
    float cp = sqrtf(d2);                       // cost_point
    float cc = -(id ? p1 : p0);                 // cost_class
    float ga = __expf(d2 * (-1.0f / 200.0f));   // SIGMA=10 -> 1/(2*sigma^2)
    float cm = inside ? (1.0f - ga) : 10.0f;    // cost_mask
    return cp + cc + cm;
}

__global__ __launch_bounds__(TB) void cost_kernel(
        const float4* __restrict__ qdata,
        const unsigned long long* __restrict__ packed,
        const float* __restrict__ tpts,
        const int* __restrict__ tids,
        float* __restrict__ out,
        int T) {
    const int q = blockIdx.x;
    const float4 qd = qdata[q];                 // broadcast
    const int g  = q >> 6;
    const int bp = q & 63;
    const unsigned long long* prow0 = packed + (size_t)(g << 1) * T; // half 0
    const unsigned long long* prow1 = prow0 + T;                     // half 1

    const int j = threadIdx.x;                  // T == 4*TB (1024/256)
    float4 tp01 = ((const float4*)tpts)[2 * j]; // (x0,y0,x1,y1)
    float4 tp23 = ((const float4*)tpts)[2 * j + 1];
    int4   id4  = ((const int4*)tids)[j];
    ulonglong2 a01 = ((const ulonglong2*)prow0)[2 * j];
    ulonglong2 a23 = ((const ulonglong2*)prow0)[2 * j + 1];
    ulonglong2 b01 = ((const ulonglong2*)prow1)[2 * j];
    ulonglong2 b23 = ((const ulonglong2*)prow1)[2 * j + 1];
    unsigned long long m0 = a01.x | b01.x;
    unsigned long long m1 = a01.y | b01.y;
    unsigned long long m2 = a23.x | b23.x;
    unsigned long long m3 = a23.y | b23.y;

    f32x4 o;
    o.x = costf(qd.x, qd.y, qd.z, qd.w, tp01.x, tp01.y, id4.x,
                (unsigned int)((m0 >> bp) & 1ull));
    o.y = costf(qd.x, qd.y, qd.z, qd.w, tp01.z, tp01.w, id4.y,
                (unsigned int)((m1 >> bp) & 1ull));
    o.z = costf(qd.x, qd.y, qd.z, qd.w, tp23.x, tp23.y, id4.z,
                (unsigned int)((m2 >> bp) & 1ull));
    o.w = costf(qd.x, qd.y, qd.z, qd.w, tp23.z, tp23.w, id4.w,
                (unsigned int)((m3 >> bp) & 1ull));

    __builtin_nontemporal_store(o, (f32x4*)(out + (size_t)q * T) + j);
}

// ---------------------------------------------------------------------------
extern "C" void kernel_launch(void* const* d_in, const int* in_sizes, int n_in,
                              void* d_out, int out_size, void* d_ws, size_t ws_size,
                              hipStream_t stream) {
    const float* logits = (const float*)d_in[0];          // [bs,nq,2] f32
    const float* points = (const float*)d_in[1];          // [bs,nq,2] f32
    const float* tpts   = (const float*)d_in[2];          // [T,2] f32
    const int*   tids   = (const int*)d_in[3];            // [T] i32
    const unsigned char* masks = (const unsigned char*)d_in[4]; // [T,H,W] bool
    const int*   img_h  = (const int*)d_in[5];            // scalar
    const int*   img_w  = (const int*)d_in[6];            // scalar
    float* out = (float*)d_out;

    const int Q  = in_sizes[1] / 2;                       // 16384
    const int T  = in_sizes[3];                           // 1024
    const int HW = (int)(in_sizes[4] / (size_t)T);        // 262144

    // ws layout: [ qdata float4 x Q | offs int x Q | packed u64 x (Q/64)*2*T ]
    char* ws = (char*)d_ws;
    float4* qdata = (float4*)ws;
    int*    offs  = (int*)(ws + (size_t)Q * 16);
    unsigned long long* packed =
        (unsigned long long*)(ws + (size_t)Q * 16 + (size_t)Q * 4);

    prep_kernel<<<(Q + TB - 1) / TB, TB, 0, stream>>>(
        logits, points, img_h, img_w, qdata, offs, Q);

    // two blocks per target (one per half-slice), 16KB dynamic LDS each
    pack_gather_kernel<<<2 * T, TB, HW / 16, stream>>>(
        masks, offs, packed, Q, T, HW);

    cost_kernel<<<Q, TB, 0, stream>>>(qdata, packed, tpts, tids, out, T);
}